// Round 7
// baseline (242.742 us; speedup 1.0000x reference)
//
#include <hip/hip_runtime.h>
#include <hip/hip_bf16.h>
#include <math.h>
#include <stdint.h>

typedef _Float16 f16;
typedef _Float16 f16x8 __attribute__((ext_vector_type(8)));
typedef float f32x16 __attribute__((ext_vector_type(16)));

#define DIM 256
#define LOSCALE 2048.0f
#define INV_LOSCALE (1.0f/2048.0f)

// B' stream: 4096 codes x 256 depth x {hi,lo}, fragment-major:
// byte offset = col*32768 + s*2048 + t*1024 + lane*16
// (col 0..127 = 32 codes each, k-step s 0..15, t 0:hi 1:lo)
// lane l holds 16B = e[code=col*32+(l&31)][depth=s*16+(l>>5)*8 .. +8]
#define BP_BYTES (4096u*1024u + 16384u)   // 4 MB stream + pad

#define GLOAD16(gp, lp) __builtin_amdgcn_global_load_lds( \
    (const __attribute__((address_space(1))) void*)(gp),  \
    (__attribute__((address_space(3))) void*)(lp), 16, 0, 0)

// ---------------------------------------------------------------------------
// pack codebook into fragment-major hi/lo f16 stream
// ---------------------------------------------------------------------------
__global__ void vq_pack2(const float* __restrict__ emb, f16* __restrict__ bp)
{
    int o = blockIdx.x * blockDim.x + threadIdx.x;   // one per 16B chunk, 262144
    int l = o & 63;
    int b = o >> 6;
    int t   = b & 1;
    int s   = (b >> 1) & 15;
    int col = b >> 5;
    int code  = col * 32 + (l & 31);
    int depth = s * 16 + (l >> 5) * 8;
    const float* gp = emb + (size_t)code * DIM + depth;
    float4 x0 = *(const float4*)gp;
    float4 x1 = *(const float4*)(gp + 4);
    float xs[8] = {x0.x, x0.y, x0.z, x0.w, x1.x, x1.y, x1.z, x1.w};
    f16x8 v;
    #pragma unroll
    for (int j = 0; j < 8; ++j) {
        f16 h = (f16)xs[j];
        v[j] = t ? (f16)((xs[j] - (float)h) * LOSCALE) : h;
    }
    *(f16x8*)(bp + (size_t)o * 8) = v;
}

// ||e_k||^2, one 64-thread block per code (fp32, full precision)
__global__ void vq_e2(const float* __restrict__ emb, float* __restrict__ e2) {
    int k = blockIdx.x;
    int l = threadIdx.x;
    float4 v = ((const float4*)(emb + (size_t)k * DIM))[l];
    float s = v.x * v.x + v.y * v.y + v.z * v.z + v.w * v.w;
    #pragma unroll
    for (int off = 32; off; off >>= 1) s += __shfl_xor(s, off);
    if (l == 0) e2[k] = s;
}

__global__ void vq_zero(int* __restrict__ p, int n) {
    int i = blockIdx.x * blockDim.x + threadIdx.x;
    if (i < n) p[i] = 0;
}

// ---------------------------------------------------------------------------
// MFMA argmin, half-K blocks for cross-block pipe overlap.
// Block: 256 thr = 4 row-tile waves, 128 rows, ONE code-half (2048 codes).
// Grid: (N/128) x 2 halves; 2 independent blocks/CU (66KB LDS each) whose
// barriers interleave -> LDS-read phase of one overlaps MFMA of the other.
// A hi/lo in regs; B col (32KB) double-buffered via global_load_lds.
// Output: per-row partial u64 key (monotonic dist<<32 | code) to ws.
// ---------------------------------------------------------------------------
__global__ __launch_bounds__(256, 2) void vq_argmin6(
    const float* __restrict__ z, const char* __restrict__ bp,
    const float* __restrict__ e2, unsigned long long* __restrict__ part)
{
    __shared__ __align__(16) char lds[2][32768];

    const int t    = threadIdx.x;
    const int lane = t & 63;
    const int rt   = t >> 6;               // row-tile 0..3
    const int hw   = blockIdx.x & 1;       // code half
    const int rg   = blockIdx.x >> 1;      // row group
    const int l31  = lane & 31;
    const int hi5  = lane >> 5;
    const int rowbase = rg * 128 + rt * 32;

    // ---- A panel to registers: row = l31, depth chunk hi5*8 per k-step ----
    f16x8 a_h[16], a_l[16];
    {
        const float* zr = z + (size_t)(rowbase + l31) * DIM + hi5 * 8;
        #pragma unroll
        for (int s = 0; s < 16; ++s) {
            float4 x0 = *(const float4*)(zr + s * 16);
            float4 x1 = *(const float4*)(zr + s * 16 + 4);
            float xs[8] = {x0.x, x0.y, x0.z, x0.w, x1.x, x1.y, x1.z, x1.w};
            #pragma unroll
            for (int j = 0; j < 8; ++j) {
                f16 h = (f16)xs[j];
                a_h[s][j] = h;
                a_l[s][j] = (f16)((xs[j] - (float)h) * LOSCALE);
            }
        }
    }

    float    bestd[16];
    unsigned bcol[4];
    #pragma unroll
    for (int q = 0; q < 16; ++q) bestd[q] = 3.4e38f;
    #pragma unroll
    for (int i = 0; i < 4; ++i) bcol[i] = 0u;

    const char* bhalf = bp + ((size_t)hw << 21);   // 2 MB half

    // stage col cc into buffer pb: 256 threads x 8 x 16B = 32KB, linear
#define STAGE(pb, cc) do {                                                    \
    const char* src_ = bhalf + ((size_t)(cc) << 15) + (size_t)t * 16;         \
    char* dst_ = lds[pb] + t * 16;                                            \
    _Pragma("unroll")                                                         \
    for (int i_ = 0; i_ < 8; ++i_)                                            \
        GLOAD16(src_ + i_ * 4096, dst_ + i_ * 4096);                          \
    } while (0)

    STAGE(0, 0);
    __syncthreads();
    int cur = 0;

    for (int c = 0; c < 64; ++c) {
        if (c < 63) STAGE(cur ^ 1, c + 1);

        float e2c = e2[hw * 2048 + c * 32 + l31];
        f32x16 acc0, acc1a, acc1b;
        #pragma unroll
        for (int q = 0; q < 16; ++q) { acc0[q] = 0.0f; acc1a[q] = 0.0f; acc1b[q] = 0.0f; }

        const char* bb = lds[cur];
        __builtin_amdgcn_s_setprio(1);
        #pragma unroll
        for (int s = 0; s < 16; ++s) {
            f16x8 bh = *(const f16x8*)(bb + s * 2048 + lane * 16);
            f16x8 bl = *(const f16x8*)(bb + s * 2048 + 1024 + lane * 16);
            acc0  = __builtin_amdgcn_mfma_f32_32x32x16_f16(a_h[s], bh, acc0,  0, 0, 0);
            acc1a = __builtin_amdgcn_mfma_f32_32x32x16_f16(a_h[s], bl, acc1a, 0, 0, 0);
            acc1b = __builtin_amdgcn_mfma_f32_32x32x16_f16(a_l[s], bh, acc1b, 0, 0, 0);
        }
        __builtin_amdgcn_s_setprio(0);

        #pragma unroll
        for (int q = 0; q < 16; ++q) {
            float dot  = fmaf(acc1a[q] + acc1b[q], INV_LOSCALE, acc0[q]);
            float dist = fmaf(-2.0f, dot, e2c);
            bool  lt   = dist < bestd[q];
            bestd[q]   = lt ? dist : bestd[q];
            const unsigned sh = (unsigned)((q & 3) * 8);
            unsigned nv = (bcol[q >> 2] & ~(0xFFu << sh)) | ((unsigned)c << sh);
            bcol[q >> 2] = lt ? nv : bcol[q >> 2];
        }

        __syncthreads();   // staged col visible; buf[cur] free for overwrite
        cur ^= 1;
    }
#undef STAGE

    // ---- per-wave reduce across 32 code-lanes; write partial keys ----
    #pragma unroll
    for (int q = 0; q < 16; ++q) {
        float    d = bestd[q];
        unsigned c = (unsigned)(hw * 2048) +
                     ((bcol[q >> 2] >> ((q & 3) * 8)) & 0xFFu) * 32u + (unsigned)l31;
        #pragma unroll
        for (int o2 = 16; o2; o2 >>= 1) {
            float    od = __shfl_xor(d, o2);
            unsigned oc = __shfl_xor(c, o2);
            if (od < d || (od == d && oc < c)) { d = od; c = oc; }
        }
        if (l31 == 0) {
            int row = (q & 3) + 8 * (q >> 2) + 4 * hi5;
            unsigned u   = __float_as_uint(d);
            unsigned key = u ^ (unsigned)(((int)u >> 31) | 0x80000000);
            part[(size_t)hw * 32768 + rowbase + row] =
                ((unsigned long long)key << 32) | c;
        }
    }
}

// combine the two half-K partials -> final float index
__global__ void vq_combine(const unsigned long long* __restrict__ part,
                           float* __restrict__ idxf, int N)
{
    int i = blockIdx.x * blockDim.x + threadIdx.x;
    if (i >= N) return;
    unsigned long long a = part[i];
    unsigned long long b = part[(size_t)N + i];
    unsigned long long m = b < a ? b : a;
    idxf[i] = (float)(unsigned)(m & 0xffffffffu);
}

// ------------------------- round-1 fallback argmin -------------------------
__global__ __launch_bounds__(256, 2) void vq_argmin_f32(
    const float* __restrict__ z, const float* __restrict__ emb,
    const float* __restrict__ e2, float* __restrict__ idxf, int K)
{
    __shared__ float zs[64 * 36];
    __shared__ float es[128 * 36];
    const int t = threadIdx.x;
    const int tx = t & 15;
    const int ty = t >> 4;
    const int rowbase = blockIdx.x * 64;
    const float* zbase = z + (size_t)rowbase * DIM;
    float best[4]; int bidx[4];
    #pragma unroll
    for (int i = 0; i < 4; ++i) { best[i] = 3.4e38f; bidx[i] = 0; }
    for (int kt = 0; kt < K; kt += 128) {
        float acc[4][8];
        #pragma unroll
        for (int i = 0; i < 4; ++i)
            #pragma unroll
            for (int j = 0; j < 8; ++j) acc[i][j] = 0.0f;
        for (int dc = 0; dc < DIM; dc += 32) {
            { int lr = t >> 2, o = (t & 3) * 8;
              const float* gp = zbase + (size_t)lr * DIM + dc + o;
              *(float4*)&zs[lr*36+o]   = *(const float4*)gp;
              *(float4*)&zs[lr*36+o+4] = *(const float4*)(gp+4); }
            { int lc = t >> 1, o = (t & 1) * 16;
              const float* gp = emb + (size_t)(kt+lc) * DIM + dc + o;
              *(float4*)&es[lc*36+o]    = *(const float4*)gp;
              *(float4*)&es[lc*36+o+4]  = *(const float4*)(gp+4);
              *(float4*)&es[lc*36+o+8]  = *(const float4*)(gp+8);
              *(float4*)&es[lc*36+o+12] = *(const float4*)(gp+12); }
            __syncthreads();
            const float* zp = &zs[(ty*4)*36];
            const float* ep = &es[tx*36];
            #pragma unroll
            for (int d = 0; d < 32; d += 4) {
                float4 zv[4], ev[8];
                #pragma unroll
                for (int i = 0; i < 4; ++i) zv[i] = *(const float4*)&zp[i*36+d];
                #pragma unroll
                for (int j = 0; j < 8; ++j) ev[j] = *(const float4*)&ep[j*16*36+d];
                #pragma unroll
                for (int i = 0; i < 4; ++i)
                    #pragma unroll
                    for (int j = 0; j < 8; ++j) {
                        acc[i][j] += zv[i].x*ev[j].x; acc[i][j] += zv[i].y*ev[j].y;
                        acc[i][j] += zv[i].z*ev[j].z; acc[i][j] += zv[i].w*ev[j].w;
                    }
            }
            __syncthreads();
        }
        #pragma unroll
        for (int j = 0; j < 8; ++j) {
            int c = kt + tx + 16*j;
            float ev2 = e2[c];
            #pragma unroll
            for (int i = 0; i < 4; ++i) {
                float dist = ev2 - 2.0f*acc[i][j];
                if (dist < best[i] || (dist == best[i] && c < bidx[i])) { best[i]=dist; bidx[i]=c; }
            }
        }
    }
    #pragma unroll
    for (int i = 0; i < 4; ++i) {
        float bd = best[i]; int bi = bidx[i];
        #pragma unroll
        for (int off = 8; off; off >>= 1) {
            float od = __shfl_xor(bd, off); int oi = __shfl_xor(bi, off);
            if (od < bd || (od == bd && oi < bi)) { bd = od; bi = oi; }
        }
        if (tx == 0) idxf[rowbase + ty*4 + i] = (float)bi;
    }
}

// ------------------------------ epilogue ops -------------------------------
__global__ void vq_gather(const float* __restrict__ emb,
                          const float* __restrict__ idxf,
                          float* __restrict__ zq, int N)
{
    int n = blockIdx.x * 4 + (threadIdx.x >> 6);
    int l = threadIdx.x & 63;
    if (n >= N) return;
    int idx = (int)idxf[n];
    ((float4*)(zq + (size_t)n * DIM))[l] = ((const float4*)(emb + (size_t)idx * DIM))[l];
}

__global__ void vq_hist(const float* __restrict__ idxf, int* __restrict__ counts, int N) {
    int n = blockIdx.x * blockDim.x + threadIdx.x;
    if (n < N) atomicAdd(&counts[(int)idxf[n]], 1);
}

__global__ void vq_ppl(const int* __restrict__ counts, float invN,
                       float* __restrict__ out, int K)
{
    int t = threadIdx.x;
    float s = 0.0f;
    for (int k = t; k < K; k += 256) {
        float p = (float)counts[k] * invN;
        s += p * logf(p + 1e-10f);
    }
    #pragma unroll
    for (int off = 32; off; off >>= 1) s += __shfl_xor(s, off);
    __shared__ float wsum[4];
    if ((t & 63) == 0) wsum[t >> 6] = s;
    __syncthreads();
    if (t == 0) out[0] = expf(-(wsum[0] + wsum[1] + wsum[2] + wsum[3]));
}

extern "C" void kernel_launch(void* const* d_in, const int* in_sizes, int n_in,
                              void* d_out, int out_size, void* d_ws, size_t ws_size,
                              hipStream_t stream)
{
    const float* z   = (const float*)d_in[0];
    const float* emb = (const float*)d_in[1];
    const int N = in_sizes[0] / DIM;   // 32768
    const int K = in_sizes[1] / DIM;   // 4096

    float* out  = (float*)d_out;
    float* zq   = out;
    float* idxf = out + (size_t)N * DIM;
    float* ppl  = idxf + N;

    const size_t PART_BYTES = 2ull * 32768 * sizeof(unsigned long long);  // 512 KB
    const size_t NEED = (size_t)BP_BYTES + 16384 + 16384 + PART_BYTES;

    if (ws_size >= NEED && K == 4096 && N == 32768) {
        f16*   bpk    = (f16*)d_ws;
        float* e2     = (float*)((char*)d_ws + BP_BYTES);
        int*   counts = (int*)((char*)d_ws + BP_BYTES + 16384);
        unsigned long long* part =
            (unsigned long long*)((char*)d_ws + BP_BYTES + 32768);

        vq_pack2<<<1024, 256, 0, stream>>>(emb, bpk);
        vq_e2<<<K, 64, 0, stream>>>(emb, e2);
        vq_zero<<<(K + 255) / 256, 256, 0, stream>>>(counts, K);
        vq_argmin6<<<(N / 128) * 2, 256, 0, stream>>>(z, (const char*)bpk, e2, part);
        vq_combine<<<N / 256, 256, 0, stream>>>(part, idxf, N);
        vq_gather<<<N / 4, 256, 0, stream>>>(emb, idxf, zq, N);
        vq_hist<<<(N + 255) / 256, 256, 0, stream>>>(idxf, counts, N);
        vq_ppl<<<1, 256, 0, stream>>>(counts, 1.0f / (float)N, ppl, K);
    } else {
        float* e2     = (float*)d_ws;
        int*   counts = (int*)((char*)d_ws + (size_t)K * sizeof(float));
        vq_e2<<<K, 64, 0, stream>>>(emb, e2);
        vq_zero<<<(K + 255) / 256, 256, 0, stream>>>(counts, K);
        vq_argmin_f32<<<N / 64, 256, 0, stream>>>(z, emb, e2, idxf, K);
        vq_gather<<<N / 4, 256, 0, stream>>>(emb, idxf, zq, N);
        vq_hist<<<(N + 255) / 256, 256, 0, stream>>>(idxf, counts, N);
        vq_ppl<<<1, 256, 0, stream>>>(counts, 1.0f / (float)N, ppl, K);
    }
}

// Round 8
// 241.047 us; speedup vs baseline: 1.0070x; 1.0070x over previous
//
#include <hip/hip_runtime.h>
#include <hip/hip_bf16.h>
#include <math.h>
#include <stdint.h>

typedef _Float16 f16;
typedef _Float16 f16x8 __attribute__((ext_vector_type(8)));
typedef float f32x16 __attribute__((ext_vector_type(16)));

#define DIM 256
#define LOSCALE 2048.0f
#define INV_LOSCALE (1.0f/2048.0f)

// B' stream: 4096 codes x 256 depth x {hi,lo}, fragment-major:
// byte offset = col*32768 + s*2048 + t*1024 + lane*16
// (col 0..127 = 32 codes each, k-step s 0..15, t 0:hi 1:lo)
// lane l holds 16B = e[code=col*32+(l&31)][depth=s*16+(l>>5)*8 .. +8]
// Unit = half-col = 16KB (s 0..7 or 8..15). 32KB pad for uniform tail staging.
#define BP_BYTES (4096u*1024u + 32768u)

#define GLOAD16(gp, lp) __builtin_amdgcn_global_load_lds( \
    (const __attribute__((address_space(1))) void*)(gp),  \
    (__attribute__((address_space(3))) void*)(lp), 16, 0, 0)

// ---------------------------------------------------------------------------
// pack codebook into fragment-major hi/lo f16 stream
// ---------------------------------------------------------------------------
__global__ void vq_pack2(const float* __restrict__ emb, f16* __restrict__ bp)
{
    int o = blockIdx.x * blockDim.x + threadIdx.x;   // one per 16B chunk, 262144
    int l = o & 63;
    int b = o >> 6;
    int t   = b & 1;
    int s   = (b >> 1) & 15;
    int col = b >> 5;
    int code  = col * 32 + (l & 31);
    int depth = s * 16 + (l >> 5) * 8;
    const float* gp = emb + (size_t)code * DIM + depth;
    float4 x0 = *(const float4*)gp;
    float4 x1 = *(const float4*)(gp + 4);
    float xs[8] = {x0.x, x0.y, x0.z, x0.w, x1.x, x1.y, x1.z, x1.w};
    f16x8 v;
    #pragma unroll
    for (int j = 0; j < 8; ++j) {
        f16 h = (f16)xs[j];
        v[j] = t ? (f16)((xs[j] - (float)h) * LOSCALE) : h;
    }
    *(f16x8*)(bp + (size_t)o * 8) = v;
}

// ||e_k||^2, one 64-thread block per code (fp32, full precision)
__global__ void vq_e2(const float* __restrict__ emb, float* __restrict__ e2) {
    int k = blockIdx.x;
    int l = threadIdx.x;
    float4 v = ((const float4*)(emb + (size_t)k * DIM))[l];
    float s = v.x * v.x + v.y * v.y + v.z * v.z + v.w * v.w;
    #pragma unroll
    for (int off = 32; off; off >>= 1) s += __shfl_xor(s, off);
    if (l == 0) e2[k] = s;
}

__global__ void vq_zero(int* __restrict__ p, int n) {
    int i = blockIdx.x * blockDim.x + threadIdx.x;
    if (i < n) p[i] = 0;
}

// ---------------------------------------------------------------------------
// MFMA argmin, T3/T4 schedule: 4 x 16KB B-buffers, counted vmcnt, raw
// s_barrier (no vmcnt(0) drains in the main loop). 256 thr = 4 row-tile
// waves, 128 rows, one code half (2048 codes = 128 units of 8 k-steps).
// Prefetch depth 2 units (8 gloads/thread in flight, wait vmcnt(8)).
// ---------------------------------------------------------------------------
__global__ __launch_bounds__(256, 2) void vq_argmin7(
    const float* __restrict__ z, const char* __restrict__ bp,
    const float* __restrict__ e2, unsigned long long* __restrict__ part)
{
    __shared__ __align__(16) char bufs[4][16384];   // 64 KB
    __shared__ float e2s[2048];                     // 8 KB

    const int t    = threadIdx.x;
    const int lane = t & 63;
    const int rt   = t >> 6;               // row-tile 0..3
    const int hw   = blockIdx.x & 1;       // code half
    const int rg   = blockIdx.x >> 1;      // row group
    const int l31  = lane & 31;
    const int hi5  = lane >> 5;
    const int rowbase = rg * 128 + rt * 32;

    // ---- e2 half to LDS (keeps main loop free of extra vmem ops) ----
    *(float4*)&e2s[t * 8]     = *(const float4*)(e2 + hw * 2048 + t * 8);
    *(float4*)&e2s[t * 8 + 4] = *(const float4*)(e2 + hw * 2048 + t * 8 + 4);

    // ---- A panel to registers: row = l31, depth chunk hi5*8 per k-step ----
    f16x8 a_h[16], a_l[16];
    {
        const float* zr = z + (size_t)(rowbase + l31) * DIM + hi5 * 8;
        #pragma unroll
        for (int s = 0; s < 16; ++s) {
            float4 x0 = *(const float4*)(zr + s * 16);
            float4 x1 = *(const float4*)(zr + s * 16 + 4);
            float xs[8] = {x0.x, x0.y, x0.z, x0.w, x1.x, x1.y, x1.z, x1.w};
            #pragma unroll
            for (int j = 0; j < 8; ++j) {
                f16 h = (f16)xs[j];
                a_h[s][j] = h;
                a_l[s][j] = (f16)((xs[j] - (float)h) * LOSCALE);
            }
        }
    }
    __syncthreads();   // e2s visible; all pre-loop vmem drained (full drain OK once)

    float    bestd[16];
    unsigned bcol[4];
    #pragma unroll
    for (int q = 0; q < 16; ++q) bestd[q] = 3.4e38f;
    #pragma unroll
    for (int i = 0; i < 4; ++i) bcol[i] = 0u;

    const char* bhalf = bp + ((size_t)hw << 21);   // 2 MB half

    // stage unit uu (16KB) into buffer pb: 256 thr x 4 x 16B, linear
#define STAGE(pb, uu) do {                                                    \
    const char* src_ = bhalf + ((size_t)(uu) << 14) + (size_t)t * 16;         \
    char* dst_ = bufs[pb] + t * 16;                                           \
    _Pragma("unroll")                                                         \
    for (int i_ = 0; i_ < 4; ++i_)                                            \
        GLOAD16(src_ + i_ * 4096, dst_ + i_ * 4096);                          \
    } while (0)

    // compute 8 k-steps from buffer BB with A-base SB, 1-ahead read pipeline
#define COMPUTE8(BB, SB) do {                                                 \
    const char* bbp_ = (BB);                                                  \
    f16x8 bh_ = *(const f16x8*)(bbp_ + lane * 16);                            \
    f16x8 bl_ = *(const f16x8*)(bbp_ + 1024 + lane * 16);                     \
    __builtin_amdgcn_s_setprio(1);                                            \
    _Pragma("unroll")                                                         \
    for (int sl_ = 0; sl_ < 8; ++sl_) {                                       \
        f16x8 bhn_, bln_;                                                     \
        if (sl_ < 7) {                                                        \
            bhn_ = *(const f16x8*)(bbp_ + (sl_+1) * 2048 + lane * 16);        \
            bln_ = *(const f16x8*)(bbp_ + (sl_+1) * 2048 + 1024 + lane * 16); \
        }                                                                     \
        acc0  = __builtin_amdgcn_mfma_f32_32x32x16_f16(a_h[(SB)+sl_], bh_, acc0,  0,0,0); \
        acc1a = __builtin_amdgcn_mfma_f32_32x32x16_f16(a_h[(SB)+sl_], bl_, acc1a, 0,0,0); \
        acc1b = __builtin_amdgcn_mfma_f32_32x32x16_f16(a_l[(SB)+sl_], bh_, acc1b, 0,0,0); \
        if (sl_ < 7) { bh_ = bhn_; bl_ = bln_; }                              \
    }                                                                         \
    __builtin_amdgcn_s_setprio(0);                                            \
    } while (0)

#define PHASE_SYNC() do {                                                     \
    asm volatile("s_waitcnt vmcnt(8)" ::: "memory");                          \
    asm volatile("s_waitcnt lgkmcnt(0)" ::: "memory");                        \
    __builtin_amdgcn_s_barrier();                                             \
    __builtin_amdgcn_sched_barrier(0);                                        \
    } while (0)

    STAGE(0, 0);
    STAGE(1, 1);

    for (int c = 0; c < 64; ++c) {
        float e2c = e2s[c * 32 + l31];
        f32x16 acc0, acc1a, acc1b;
        #pragma unroll
        for (int q = 0; q < 16; ++q) { acc0[q] = 0.0f; acc1a[q] = 0.0f; acc1b[q] = 0.0f; }

        // phase 0: unit 2c (s 0..7); stage unit 2c+2
        STAGE((2*c + 2) & 3, 2*c + 2);
        PHASE_SYNC();
        COMPUTE8(bufs[(2*c) & 3], 0);

        // phase 1: unit 2c+1 (s 8..15); stage unit 2c+3
        STAGE((2*c + 3) & 3, 2*c + 3);
        PHASE_SYNC();
        COMPUTE8(bufs[(2*c + 1) & 3], 8);

        // epilogue: fold scales, distances, running argmin
        #pragma unroll
        for (int q = 0; q < 16; ++q) {
            float dot  = fmaf(acc1a[q] + acc1b[q], INV_LOSCALE, acc0[q]);
            float dist = fmaf(-2.0f, dot, e2c);
            bool  lt   = dist < bestd[q];
            bestd[q]   = lt ? dist : bestd[q];
            const unsigned sh = (unsigned)((q & 3) * 8);
            unsigned nv = (bcol[q >> 2] & ~(0xFFu << sh)) | ((unsigned)c << sh);
            bcol[q >> 2] = lt ? nv : bcol[q >> 2];
        }
    }
#undef STAGE
#undef COMPUTE8
#undef PHASE_SYNC

    // ---- per-wave reduce across 32 code-lanes; write partial keys ----
    #pragma unroll
    for (int q = 0; q < 16; ++q) {
        float    d = bestd[q];
        unsigned c = (unsigned)(hw * 2048) +
                     ((bcol[q >> 2] >> ((q & 3) * 8)) & 0xFFu) * 32u + (unsigned)l31;
        #pragma unroll
        for (int o2 = 16; o2; o2 >>= 1) {
            float    od = __shfl_xor(d, o2);
            unsigned oc = __shfl_xor(c, o2);
            if (od < d || (od == d && oc < c)) { d = od; c = oc; }
        }
        if (l31 == 0) {
            int row = (q & 3) + 8 * (q >> 2) + 4 * hi5;
            unsigned u   = __float_as_uint(d);
            unsigned key = u ^ (unsigned)(((int)u >> 31) | 0x80000000);
            part[(size_t)hw * 32768 + rowbase + row] =
                ((unsigned long long)key << 32) | c;
        }
    }
}

// combine the two half-K partials -> final float index
__global__ void vq_combine(const unsigned long long* __restrict__ part,
                           float* __restrict__ idxf, int N)
{
    int i = blockIdx.x * blockDim.x + threadIdx.x;
    if (i >= N) return;
    unsigned long long a = part[i];
    unsigned long long b = part[(size_t)N + i];
    unsigned long long m = b < a ? b : a;
    idxf[i] = (float)(unsigned)(m & 0xffffffffu);
}

// ------------------------- round-1 fallback argmin -------------------------
__global__ __launch_bounds__(256, 2) void vq_argmin_f32(
    const float* __restrict__ z, const float* __restrict__ emb,
    const float* __restrict__ e2, float* __restrict__ idxf, int K)
{
    __shared__ float zs[64 * 36];
    __shared__ float es[128 * 36];
    const int t = threadIdx.x;
    const int tx = t & 15;
    const int ty = t >> 4;
    const int rowbase = blockIdx.x * 64;
    const float* zbase = z + (size_t)rowbase * DIM;
    float best[4]; int bidx[4];
    #pragma unroll
    for (int i = 0; i < 4; ++i) { best[i] = 3.4e38f; bidx[i] = 0; }
    for (int kt = 0; kt < K; kt += 128) {
        float acc[4][8];
        #pragma unroll
        for (int i = 0; i < 4; ++i)
            #pragma unroll
            for (int j = 0; j < 8; ++j) acc[i][j] = 0.0f;
        for (int dc = 0; dc < DIM; dc += 32) {
            { int lr = t >> 2, o = (t & 3) * 8;
              const float* gp = zbase + (size_t)lr * DIM + dc + o;
              *(float4*)&zs[lr*36+o]   = *(const float4*)gp;
              *(float4*)&zs[lr*36+o+4] = *(const float4*)(gp+4); }
            { int lc = t >> 1, o = (t & 1) * 16;
              const float* gp = emb + (size_t)(kt+lc) * DIM + dc + o;
              *(float4*)&es[lc*36+o]    = *(const float4*)gp;
              *(float4*)&es[lc*36+o+4]  = *(const float4*)(gp+4);
              *(float4*)&es[lc*36+o+8]  = *(const float4*)(gp+8);
              *(float4*)&es[lc*36+o+12] = *(const float4*)(gp+12); }
            __syncthreads();
            const float* zp = &zs[(ty*4)*36];
            const float* ep = &es[tx*36];
            #pragma unroll
            for (int d = 0; d < 32; d += 4) {
                float4 zv[4], ev[8];
                #pragma unroll
                for (int i = 0; i < 4; ++i) zv[i] = *(const float4*)&zp[i*36+d];
                #pragma unroll
                for (int j = 0; j < 8; ++j) ev[j] = *(const float4*)&ep[j*16*36+d];
                #pragma unroll
                for (int i = 0; i < 4; ++i)
                    #pragma unroll
                    for (int j = 0; j < 8; ++j) {
                        acc[i][j] += zv[i].x*ev[j].x; acc[i][j] += zv[i].y*ev[j].y;
                        acc[i][j] += zv[i].z*ev[j].z; acc[i][j] += zv[i].w*ev[j].w;
                    }
            }
            __syncthreads();
        }
        #pragma unroll
        for (int j = 0; j < 8; ++j) {
            int c = kt + tx + 16*j;
            float ev2 = e2[c];
            #pragma unroll
            for (int i = 0; i < 4; ++i) {
                float dist = ev2 - 2.0f*acc[i][j];
                if (dist < best[i] || (dist == best[i] && c < bidx[i])) { best[i]=dist; bidx[i]=c; }
            }
        }
    }
    #pragma unroll
    for (int i = 0; i < 4; ++i) {
        float bd = best[i]; int bi = bidx[i];
        #pragma unroll
        for (int off = 8; off; off >>= 1) {
            float od = __shfl_xor(bd, off); int oi = __shfl_xor(bi, off);
            if (od < bd || (od == bd && oi < bi)) { bd = od; bi = oi; }
        }
        if (tx == 0) idxf[rowbase + ty*4 + i] = (float)bi;
    }
}

// ------------------------------ epilogue ops -------------------------------
__global__ void vq_gather(const float* __restrict__ emb,
                          const float* __restrict__ idxf,
                          float* __restrict__ zq, int N)
{
    int n = blockIdx.x * 4 + (threadIdx.x >> 6);
    int l = threadIdx.x & 63;
    if (n >= N) return;
    int idx = (int)idxf[n];
    ((float4*)(zq + (size_t)n * DIM))[l] = ((const float4*)(emb + (size_t)idx * DIM))[l];
}

__global__ void vq_hist(const float* __restrict__ idxf, int* __restrict__ counts, int N) {
    int n = blockIdx.x * blockDim.x + threadIdx.x;
    if (n < N) atomicAdd(&counts[(int)idxf[n]], 1);
}

__global__ void vq_ppl(const int* __restrict__ counts, float invN,
                       float* __restrict__ out, int K)
{
    int t = threadIdx.x;
    float s = 0.0f;
    for (int k = t; k < K; k += 256) {
        float p = (float)counts[k] * invN;
        s += p * logf(p + 1e-10f);
    }
    #pragma unroll
    for (int off = 32; off; off >>= 1) s += __shfl_xor(s, off);
    __shared__ float wsum[4];
    if ((t & 63) == 0) wsum[t >> 6] = s;
    __syncthreads();
    if (t == 0) out[0] = expf(-(wsum[0] + wsum[1] + wsum[2] + wsum[3]));
}

extern "C" void kernel_launch(void* const* d_in, const int* in_sizes, int n_in,
                              void* d_out, int out_size, void* d_ws, size_t ws_size,
                              hipStream_t stream)
{
    const float* z   = (const float*)d_in[0];
    const float* emb = (const float*)d_in[1];
    const int N = in_sizes[0] / DIM;   // 32768
    const int K = in_sizes[1] / DIM;   // 4096

    float* out  = (float*)d_out;
    float* zq   = out;
    float* idxf = out + (size_t)N * DIM;
    float* ppl  = idxf + N;

    const size_t PART_BYTES = 2ull * 32768 * sizeof(unsigned long long);  // 512 KB
    const size_t NEED = (size_t)BP_BYTES + 16384 + 16384 + PART_BYTES;

    if (ws_size >= NEED && K == 4096 && N == 32768) {
        f16*   bpk    = (f16*)d_ws;
        float* e2     = (float*)((char*)d_ws + BP_BYTES);
        int*   counts = (int*)((char*)d_ws + BP_BYTES + 16384);
        unsigned long long* part =
            (unsigned long long*)((char*)d_ws + BP_BYTES + 32768);

        vq_pack2<<<1024, 256, 0, stream>>>(emb, bpk);
        vq_e2<<<K, 64, 0, stream>>>(emb, e2);
        vq_zero<<<(K + 255) / 256, 256, 0, stream>>>(counts, K);
        vq_argmin7<<<(N / 128) * 2, 256, 0, stream>>>(z, (const char*)bpk, e2, part);
        vq_combine<<<N / 256, 256, 0, stream>>>(part, idxf, N);
        vq_gather<<<N / 4, 256, 0, stream>>>(emb, idxf, zq, N);
        vq_hist<<<(N + 255) / 256, 256, 0, stream>>>(idxf, counts, N);
        vq_ppl<<<1, 256, 0, stream>>>(counts, 1.0f / (float)N, ppl, K);
    } else {
        float* e2     = (float*)d_ws;
        int*   counts = (int*)((char*)d_ws + (size_t)K * sizeof(float));
        vq_e2<<<K, 64, 0, stream>>>(emb, e2);
        vq_zero<<<(K + 255) / 256, 256, 0, stream>>>(counts, K);
        vq_argmin_f32<<<N / 64, 256, 0, stream>>>(z, emb, e2, idxf, K);
        vq_gather<<<N / 4, 256, 0, stream>>>(emb, idxf, zq, N);
        vq_hist<<<(N + 255) / 256, 256, 0, stream>>>(idxf, counts, N);
        vq_ppl<<<1, 256, 0, stream>>>(counts, 1.0f / (float)N, ppl, K);
    }
}